// Round 1
// baseline (1719.251 us; speedup 1.0000x reference)
//
#include <hip/hip_runtime.h>
#include <math.h>

#define NN 12288
#define DD 128
#define EPSF 1e-7f
#define MAXNORM (1.0f - 1e-3f)
#define CSPLIT 4
#define CCOLS (NN / CSPLIT)      /* 3072 columns per block */
#define CSTEPS (CCOLS / 128)     /* 24 steps of 128 columns */

typedef __attribute__((ext_vector_type(8))) short short8_t;
typedef __attribute__((ext_vector_type(4))) float float4_t;
typedef unsigned short ushort_t;

__device__ __forceinline__ unsigned short f2bf(float f) {
    unsigned int u = __builtin_bit_cast(unsigned int, f);
    unsigned int r = u + 0x7FFFu + ((u >> 16) & 1u);
    return (unsigned short)(r >> 16);
}

// ---------------- Kernel 1: per-row prep ----------------
__global__ __launch_bounds__(128) void prep_kernel(
    const float* __restrict__ x, const float* __restrict__ a,
    ushort_t* __restrict__ xtb,
    float* __restrict__ wh1, float* __restrict__ wh2)
{
    const int r = blockIdx.x;
    const int t = threadIdx.x;
    const float xv = x[r * DD + t];
    const float a1 = a[t];
    const float a2 = a[DD + t];
    float s0 = xv * xv, s1 = xv * a1, s2 = xv * a2;
    #pragma unroll
    for (int o = 32; o > 0; o >>= 1) {
        s0 += __shfl_xor(s0, o);
        s1 += __shfl_xor(s1, o);
        s2 += __shfl_xor(s2, o);
    }
    __shared__ float red[6];
    const int w = t >> 6;
    if ((t & 63) == 0) { red[w * 3 + 0] = s0; red[w * 3 + 1] = s1; red[w * 3 + 2] = s2; }
    __syncthreads();
    const float sumsq = red[0] + red[3];
    const float d1    = red[1] + red[4];
    const float d2    = red[2] + red[5];
    const float nraw  = sqrtf(sumsq);
    const float nrm   = fminf(fmaxf(nraw, EPSF), 1.0f - EPSF);
    const float scale = atanhf(nrm) / nrm;
    xtb[(size_t)r * DD + t] = f2bf(xv * scale);
    if (t == 0) {
        wh1[r] = scale * d1;
        wh2[r] = scale * d2;
    }
}

// ---------------- Kernel 2: build xtB in MFMA-B-fragment-linear layout ----
// chunk C (32 j), dt: 1 KB block; element (lane, e) = xt[C*32+(lane>>4)*8+e][dt*16+(lane&15)]
__global__ __launch_bounds__(256) void swizzle_kernel(
    const ushort_t* __restrict__ xtb, ushort_t* __restrict__ xtB)
{
    __shared__ ushort_t raw[32 * 136];
    const int C = blockIdx.x;
    const int t = threadIdx.x;
    #pragma unroll
    for (int p = 0; p < 2; ++p) {
        const int idx = p * 256 + t;
        const int j = idx >> 4, cell = idx & 15;
        const uint4 v = *(const uint4*)(xtb + (size_t)(C * 32 + j) * DD + cell * 8);
        *(uint4*)&raw[j * 136 + cell * 8] = v;
    }
    __syncthreads();
    #pragma unroll
    for (int p = 0; p < 2; ++p) {
        const int oc = p * 256 + t;       // 0..511 = dt*64 + lane
        const int dt = oc >> 6;
        const int l6 = oc & 63;
        const int l15 = l6 & 15, q = l6 >> 4;
        short8_t v;
        #pragma unroll
        for (int e = 0; e < 8; ++e)
            v[e] = (short)raw[(q * 8 + e) * 136 + dt * 16 + l15];
        *(short8_t*)(xtB + (size_t)C * 4096 + oc * 8) = v;
    }
}

// ---------------- Kernel 3: flash-style MFMA attention ----------------
// grid (192, 4). Block: 4 waves, 64 rows; wave w owns 16 rows, all CCOLS
// columns of its quarter. acc lives across the whole pass (scores bounded,
// no max needed). B fragments read straight from xtB (3 MB, L2-resident,
// already fragment-linear -> coalesced dwordx4). adj is the only HBM
// stream, prefetch distance 2, no barriers in main loop, 12 KB LDS only.
__global__ __launch_bounds__(256, 2) void attn_kernel(
    const int* __restrict__ adj,
    const ushort_t* __restrict__ xtB,
    const float* __restrict__ wh1, const float* __restrict__ wh2,
    float* __restrict__ pout, float* __restrict__ plsum)
{
    __shared__ __align__(16) float wh2_lds[CCOLS];   // 12 KB

    const int t = threadIdx.x;
    const int w = t >> 6, lane = t & 63;
    const int l15 = lane & 15, quad = lane >> 4;
    const int cy = blockIdx.y;
    const int jcol0 = cy * CCOLS;
    const int rowbase = blockIdx.x * 64 + w * 16;    // wave's 16 rows

    // ---- stage wh2 window (only barrier in the kernel) ----
    #pragma unroll
    for (int m = 0; m < CCOLS / 256; ++m)
        wh2_lds[m * 256 + t] = wh2[jcol0 + m * 256 + t];
    const float wh1i = wh1[rowbase + l15];
    __syncthreads();

    const int* adj_lane = adj + (size_t)(rowbase + l15) * NN + jcol0 + quad * 8;
    const ushort_t* Bbase = xtB + (size_t)(jcol0 >> 5) * 4096 + (size_t)lane * 8;

    float4_t acc[8];
    #pragma unroll
    for (int dt = 0; dt < 8; ++dt) acc[dt] = (float4_t)0.0f;
    float lsum = 0.0f;
    int4 A0[8], A1[8], A2[8];

    auto load_step = [&](int st, int4 (&A)[8]) {
        const int* bp = adj_lane + st * 128;
        #pragma unroll
        for (int kc = 0; kc < 4; ++kc) {
            A[kc * 2 + 0] = *(const int4*)(bp + kc * 32);
            A[kc * 2 + 1] = *(const int4*)(bp + kc * 32 + 4);
        }
    };

    auto process = [&](int st, int4 (&A)[8]) {
        #pragma unroll
        for (int kc = 0; kc < 4; ++kc) {
            const int wbase = st * 128 + kc * 32 + quad * 8;
            const float4 Wa = *(const float4*)&wh2_lds[wbase];
            const float4 Wb = *(const float4*)&wh2_lds[wbase + 4];
            const int4 Aa = A[kc * 2 + 0], Ac = A[kc * 2 + 1];
            const float u0 = wh1i + Wa.x, u1 = wh1i + Wa.y;
            const float u2 = wh1i + Wa.z, u3 = wh1i + Wa.w;
            const float u4 = wh1i + Wb.x, u5 = wh1i + Wb.y;
            const float u6 = wh1i + Wb.z, u7 = wh1i + Wb.w;
            const float p0 = (Aa.x > 0) ? __expf(fmaxf(u0, 0.2f * u0)) : 0.0f;
            const float p1 = (Aa.y > 0) ? __expf(fmaxf(u1, 0.2f * u1)) : 0.0f;
            const float p2 = (Aa.z > 0) ? __expf(fmaxf(u2, 0.2f * u2)) : 0.0f;
            const float p3 = (Aa.w > 0) ? __expf(fmaxf(u3, 0.2f * u3)) : 0.0f;
            const float p4 = (Ac.x > 0) ? __expf(fmaxf(u4, 0.2f * u4)) : 0.0f;
            const float p5 = (Ac.y > 0) ? __expf(fmaxf(u5, 0.2f * u5)) : 0.0f;
            const float p6 = (Ac.z > 0) ? __expf(fmaxf(u6, 0.2f * u6)) : 0.0f;
            const float p7 = (Ac.w > 0) ? __expf(fmaxf(u7, 0.2f * u7)) : 0.0f;
            lsum += ((p0 + p1) + (p2 + p3)) + ((p4 + p5) + (p6 + p7));
            short8_t af;
            af[0] = (short)f2bf(p0); af[1] = (short)f2bf(p1);
            af[2] = (short)f2bf(p2); af[3] = (short)f2bf(p3);
            af[4] = (short)f2bf(p4); af[5] = (short)f2bf(p5);
            af[6] = (short)f2bf(p6); af[7] = (short)f2bf(p7);
            const ushort_t* Bp = Bbase + (size_t)(st * 4 + kc) * 4096;
            #pragma unroll
            for (int dt = 0; dt < 8; ++dt) {
                const short8_t Bf = *(const short8_t*)(Bp + dt * 512);
                acc[dt] = __builtin_amdgcn_mfma_f32_16x16x32_bf16(af, Bf, acc[dt], 0, 0, 0);
            }
        }
    };

    // ---- unrolled 24-step schedule, prefetch distance 2, no barriers ----
    load_step(0, A0);
    load_step(1, A1);
    #pragma unroll
    for (int st = 0; st < CSTEPS; ++st) {
        if (st + 2 < CSTEPS) {
            const int m2 = (st + 2) % 3;
            if (m2 == 0)      load_step(st + 2, A0);
            else if (m2 == 1) load_step(st + 2, A1);
            else              load_step(st + 2, A2);
        }
        const int m = st % 3;
        if (m == 0)      process(st, A0);
        else if (m == 1) process(st, A1);
        else             process(st, A2);
    }

    // ---- epilogue: one partial per column-quarter ----
    float v = lsum;
    v += __shfl_xor(v, 16);
    v += __shfl_xor(v, 32);
    if (quad == 0) plsum[(size_t)cy * NN + rowbase + l15] = v;
    #pragma unroll
    for (int dt = 0; dt < 8; ++dt)
        #pragma unroll
        for (int reg = 0; reg < 4; ++reg)
            pout[((size_t)cy * NN + rowbase + quad * 4 + reg) * DD + dt * 16 + l15]
                = acc[dt][reg];
}

// ---------------- Kernel 4: combine partials + normalize + expmap0 + proj ----
__global__ __launch_bounds__(128) void reduce_kernel(
    const float* __restrict__ pout, const float* __restrict__ plsum,
    float* __restrict__ out)
{
    const int i = blockIdx.x;
    const int t = threadIdx.x;
    float v = 0.0f;
    #pragma unroll
    for (int s = 0; s < CSPLIT; ++s) v += pout[((size_t)s * NN + i) * DD + t];
    float ls = 0.0f;
    #pragma unroll
    for (int s = 0; s < CSPLIT; ++s) ls += plsum[(size_t)s * NN + i];
    v /= ls;
    float ss = v * v;
    #pragma unroll
    for (int o = 1; o < 64; o <<= 1) ss += __shfl_xor(ss, o);
    __shared__ float r2[2];
    if ((t & 63) == 0) r2[t >> 6] = ss;
    __syncthreads();
    const float total = r2[0] + r2[1];
    const float nraw = sqrtf(total);
    const float nv   = fmaxf(nraw, EPSF);
    const float th   = tanhf(nv);
    const float ysc  = th / nv;
    const float nyr  = ysc * nraw;
    const float ny   = fmaxf(nyr, EPSF);
    const float psc  = (ny > MAXNORM) ? (MAXNORM / ny) : 1.0f;
    const float os   = ysc * psc;
    out[(size_t)i * DD + t] = v * os;
}

extern "C" void kernel_launch(void* const* d_in, const int* in_sizes, int n_in,
                              void* d_out, int out_size, void* d_ws, size_t ws_size,
                              hipStream_t stream) {
    const float* x   = (const float*)d_in[0];
    const int*   adj = (const int*)d_in[1];
    const float* a   = (const float*)d_in[2];
    float* out = (float*)d_out;

    // ---- workspace layout (~31 MB; ws is ~2.4 GB) ----
    char* ws = (char*)d_ws;
    ushort_t* xtb = (ushort_t*)ws;  ws += (size_t)NN * DD * sizeof(ushort_t);
    ushort_t* xtB = (ushort_t*)ws;  ws += (size_t)NN * DD * sizeof(ushort_t);
    float* wh1 = (float*)ws;        ws += NN * sizeof(float);
    float* wh2 = (float*)ws;        ws += NN * sizeof(float);
    float* plsum = (float*)ws;      ws += (size_t)CSPLIT * NN * sizeof(float);
    float* pout  = (float*)ws;

    prep_kernel<<<NN, 128, 0, stream>>>(x, a, xtb, wh1, wh2);
    swizzle_kernel<<<NN / 32, 256, 0, stream>>>(xtb, xtB);
    attn_kernel<<<dim3(NN / 64, CSPLIT), 256, 0, stream>>>(
        adj, xtB, wh1, wh2, pout, plsum);
    reduce_kernel<<<NN, 128, 0, stream>>>(pout, plsum, out);
}

// Round 2
// 1028.720 us; speedup vs baseline: 1.6713x; 1.6713x over previous
//
#include <hip/hip_runtime.h>
#include <math.h>

#define NN 12288
#define DD 128
#define EPSF 1e-7f
#define MAXNORM (1.0f - 1e-3f)
#define CSPLIT 4
#define CCOLS (NN / CSPLIT)      /* 3072 columns per block */
#define CSTEPS (CCOLS / 128)     /* 24 steps of 128 columns */
#define BITS_U64_PER_ROW (NN / 64)   /* 192 */

typedef __attribute__((ext_vector_type(8))) short short8_t;
typedef __attribute__((ext_vector_type(4))) float float4_t;
typedef unsigned short ushort_t;
typedef unsigned long long u64_t;

__device__ __forceinline__ unsigned short f2bf(float f) {
    unsigned int u = __builtin_bit_cast(unsigned int, f);
    unsigned int r = u + 0x7FFFu + ((u >> 16) & 1u);
    return (unsigned short)(r >> 16);
}

// ---------------- Kernel 1: per-row prep ----------------
__global__ __launch_bounds__(128) void prep_kernel(
    const float* __restrict__ x, const float* __restrict__ a,
    ushort_t* __restrict__ xtb,
    float* __restrict__ wh1, float* __restrict__ wh2)
{
    const int r = blockIdx.x;
    const int t = threadIdx.x;
    const float xv = x[r * DD + t];
    const float a1 = a[t];
    const float a2 = a[DD + t];
    float s0 = xv * xv, s1 = xv * a1, s2 = xv * a2;
    #pragma unroll
    for (int o = 32; o > 0; o >>= 1) {
        s0 += __shfl_xor(s0, o);
        s1 += __shfl_xor(s1, o);
        s2 += __shfl_xor(s2, o);
    }
    __shared__ float red[6];
    const int w = t >> 6;
    if ((t & 63) == 0) { red[w * 3 + 0] = s0; red[w * 3 + 1] = s1; red[w * 3 + 2] = s2; }
    __syncthreads();
    const float sumsq = red[0] + red[3];
    const float d1    = red[1] + red[4];
    const float d2    = red[2] + red[5];
    const float nraw  = sqrtf(sumsq);
    const float nrm   = fminf(fmaxf(nraw, EPSF), 1.0f - EPSF);
    const float scale = atanhf(nrm) / nrm;
    xtb[(size_t)r * DD + t] = f2bf(xv * scale);
    if (t == 0) {
        wh1[r] = scale * d1;
        wh2[r] = scale * d2;
    }
}

// ---------------- Kernel 2: build xtB in MFMA-B-fragment-linear layout ----
// chunk C (32 j), dt: 1 KB block; element (lane, e) = xt[C*32+(lane>>4)*8+e][dt*16+(lane&15)]
__global__ __launch_bounds__(256) void swizzle_kernel(
    const ushort_t* __restrict__ xtb, ushort_t* __restrict__ xtB)
{
    __shared__ ushort_t raw[32 * 136];
    const int C = blockIdx.x;
    const int t = threadIdx.x;
    #pragma unroll
    for (int p = 0; p < 2; ++p) {
        const int idx = p * 256 + t;
        const int j = idx >> 4, cell = idx & 15;
        const uint4 v = *(const uint4*)(xtb + (size_t)(C * 32 + j) * DD + cell * 8);
        *(uint4*)&raw[j * 136 + cell * 8] = v;
    }
    __syncthreads();
    #pragma unroll
    for (int p = 0; p < 2; ++p) {
        const int oc = p * 256 + t;       // 0..511 = dt*64 + lane
        const int dt = oc >> 6;
        const int l6 = oc & 63;
        const int l15 = l6 & 15, q = l6 >> 4;
        short8_t v;
        #pragma unroll
        for (int e = 0; e < 8; ++e)
            v[e] = (short)raw[(q * 8 + e) * 136 + dt * 16 + l15];
        *(short8_t*)(xtB + (size_t)C * 4096 + oc * 8) = v;
    }
}

// ---------------- Kernel 2b: compress adj (int32 0/1) into a bitmask ----
// 604 MB -> 18.9 MB, read perfectly contiguously (256 B per wave-inst).
// u64 word w of row i holds cols [w*64, w*64+64), LSB = lowest col.
__global__ __launch_bounds__(256) void bitify_kernel(
    const int* __restrict__ adj, u64_t* __restrict__ bits)
{
    const int i = blockIdx.x;                 // row
    const int w = threadIdx.x >> 6;           // wave 0..3
    const int lane = threadIdx.x & 63;
    const int* rp = adj + (size_t)i * NN;
    #pragma unroll 8
    for (int k = 0; k < BITS_U64_PER_ROW / 4; ++k) {   // 48 iters per wave
        const int word = w * (BITS_U64_PER_ROW / 4) + k;
        const int v = rp[word * 64 + lane];
        const u64_t b = __ballot(v > 0);
        if (lane == 0) bits[(size_t)i * BITS_U64_PER_ROW + word] = b;
    }
}

// ---------------- Kernel 3: flash-style MFMA attention (bitmask adj) ----
// grid (192, 4), 3 blocks/CU. Wave owns 16 rows x 3072 cols; acc lives in
// registers across the whole pass (scores bounded, no running max needed).
// Adjacency comes from the 19 MB bitmask (16 B/lane/step, L2-resident);
// B fragments read from xtB (3 MB, per-XCD-L2-resident, fragment-linear ->
// coalesced 1 KB dwordx4). No big prefetch buffers -> no scratch spill.
__global__ __launch_bounds__(256, 3) void attn_kernel(
    const u64_t* __restrict__ bits,
    const ushort_t* __restrict__ xtB,
    const float* __restrict__ wh1, const float* __restrict__ wh2,
    float* __restrict__ pout, float* __restrict__ plsum)
{
    __shared__ __align__(16) float wh2_lds[CCOLS];   // 12 KB

    const int t = threadIdx.x;
    const int w = t >> 6, lane = t & 63;
    const int l15 = lane & 15, quad = lane >> 4;
    const int cy = blockIdx.y;
    const int jcol0 = cy * CCOLS;
    const int rowbase = blockIdx.x * 64 + w * 16;    // wave's 16 rows

    #pragma unroll
    for (int m = 0; m < CCOLS / 256; ++m)
        wh2_lds[m * 256 + t] = wh2[jcol0 + m * 256 + t];
    const float wh1i = wh1[rowbase + l15];
    __syncthreads();

    // uint4 = 128 bits = one step's columns for this lane's row
    const uint4* bitp = (const uint4*)bits
                      + (size_t)(rowbase + l15) * (NN / 128) + cy * CSTEPS;
    const ushort_t* Bbase = xtB + (size_t)(jcol0 >> 5) * 4096 + (size_t)lane * 8;

    float4_t acc[8];
    #pragma unroll
    for (int dt = 0; dt < 8; ++dt) acc[dt] = (float4_t)0.0f;
    float lsum = 0.0f;

    auto process = [&](int st, const uint4& A) {
        const int sb = st * 128;
        #pragma unroll
        for (int kc = 0; kc < 4; ++kc) {
            const unsigned word = (kc == 0) ? A.x : (kc == 1) ? A.y
                                : (kc == 2) ? A.z : A.w;
            const unsigned wq = (word >> (quad * 8)) & 0xFFu;
            const int wbase = sb + kc * 32 + quad * 8;
            const float4 Wa = *(const float4*)&wh2_lds[wbase];
            const float4 Wb = *(const float4*)&wh2_lds[wbase + 4];
            const float u0 = wh1i + Wa.x, u1 = wh1i + Wa.y;
            const float u2 = wh1i + Wa.z, u3 = wh1i + Wa.w;
            const float u4 = wh1i + Wb.x, u5 = wh1i + Wb.y;
            const float u6 = wh1i + Wb.z, u7 = wh1i + Wb.w;
            const float p0 = (wq & 1u)   ? __expf(fmaxf(u0, 0.2f * u0)) : 0.0f;
            const float p1 = (wq & 2u)   ? __expf(fmaxf(u1, 0.2f * u1)) : 0.0f;
            const float p2 = (wq & 4u)   ? __expf(fmaxf(u2, 0.2f * u2)) : 0.0f;
            const float p3 = (wq & 8u)   ? __expf(fmaxf(u3, 0.2f * u3)) : 0.0f;
            const float p4 = (wq & 16u)  ? __expf(fmaxf(u4, 0.2f * u4)) : 0.0f;
            const float p5 = (wq & 32u)  ? __expf(fmaxf(u5, 0.2f * u5)) : 0.0f;
            const float p6 = (wq & 64u)  ? __expf(fmaxf(u6, 0.2f * u6)) : 0.0f;
            const float p7 = (wq & 128u) ? __expf(fmaxf(u7, 0.2f * u7)) : 0.0f;
            lsum += ((p0 + p1) + (p2 + p3)) + ((p4 + p5) + (p6 + p7));
            short8_t af;
            af[0] = (short)f2bf(p0); af[1] = (short)f2bf(p1);
            af[2] = (short)f2bf(p2); af[3] = (short)f2bf(p3);
            af[4] = (short)f2bf(p4); af[5] = (short)f2bf(p5);
            af[6] = (short)f2bf(p6); af[7] = (short)f2bf(p7);
            const ushort_t* Bp = Bbase + (size_t)(st * 4 + kc) * 4096;
            #pragma unroll
            for (int dt = 0; dt < 8; ++dt) {
                const short8_t Bf = *(const short8_t*)(Bp + dt * 512);
                acc[dt] = __builtin_amdgcn_mfma_f32_16x16x32_bf16(af, Bf, acc[dt], 0, 0, 0);
            }
        }
    };

    // 24 steps, 3-stage rotation, prefetch distance 2 (tiny uint4 buffers)
    uint4 A0 = bitp[0], A1 = bitp[1], A2;
    #pragma unroll 1
    for (int st = 0; st < CSTEPS; st += 3) {
        A2 = bitp[st + 2];
        process(st, A0);
        if (st + 3 < CSTEPS) A0 = bitp[st + 3];
        process(st + 1, A1);
        if (st + 4 < CSTEPS) A1 = bitp[st + 4];
        process(st + 2, A2);
    }

    // ---- epilogue: one partial per column-quarter ----
    float v = lsum;
    v += __shfl_xor(v, 16);
    v += __shfl_xor(v, 32);
    if (quad == 0) plsum[(size_t)cy * NN + rowbase + l15] = v;
    #pragma unroll
    for (int dt = 0; dt < 8; ++dt)
        #pragma unroll
        for (int reg = 0; reg < 4; ++reg)
            pout[((size_t)cy * NN + rowbase + quad * 4 + reg) * DD + dt * 16 + l15]
                = acc[dt][reg];
}

// ---------------- Kernel 4: combine partials + normalize + expmap0 + proj ----
__global__ __launch_bounds__(128) void reduce_kernel(
    const float* __restrict__ pout, const float* __restrict__ plsum,
    float* __restrict__ out)
{
    const int i = blockIdx.x;
    const int t = threadIdx.x;
    float v = 0.0f;
    #pragma unroll
    for (int s = 0; s < CSPLIT; ++s) v += pout[((size_t)s * NN + i) * DD + t];
    float ls = 0.0f;
    #pragma unroll
    for (int s = 0; s < CSPLIT; ++s) ls += plsum[(size_t)s * NN + i];
    v /= ls;
    float ss = v * v;
    #pragma unroll
    for (int o = 1; o < 64; o <<= 1) ss += __shfl_xor(ss, o);
    __shared__ float r2[2];
    if ((t & 63) == 0) r2[t >> 6] = ss;
    __syncthreads();
    const float total = r2[0] + r2[1];
    const float nraw = sqrtf(total);
    const float nv   = fmaxf(nraw, EPSF);
    const float th   = tanhf(nv);
    const float ysc  = th / nv;
    const float nyr  = ysc * nraw;
    const float ny   = fmaxf(nyr, EPSF);
    const float psc  = (ny > MAXNORM) ? (MAXNORM / ny) : 1.0f;
    const float os   = ysc * psc;
    out[(size_t)i * DD + t] = v * os;
}

extern "C" void kernel_launch(void* const* d_in, const int* in_sizes, int n_in,
                              void* d_out, int out_size, void* d_ws, size_t ws_size,
                              hipStream_t stream) {
    const float* x   = (const float*)d_in[0];
    const int*   adj = (const int*)d_in[1];
    const float* a   = (const float*)d_in[2];
    float* out = (float*)d_out;

    // ---- workspace layout (~50 MB; ws is ~2.4 GB) ----
    char* ws = (char*)d_ws;
    ushort_t* xtb = (ushort_t*)ws;  ws += (size_t)NN * DD * sizeof(ushort_t);
    ushort_t* xtB = (ushort_t*)ws;  ws += (size_t)NN * DD * sizeof(ushort_t);
    float* wh1 = (float*)ws;        ws += NN * sizeof(float);
    float* wh2 = (float*)ws;        ws += NN * sizeof(float);
    float* plsum = (float*)ws;      ws += (size_t)CSPLIT * NN * sizeof(float);
    float* pout  = (float*)ws;      ws += (size_t)CSPLIT * NN * DD * sizeof(float);
    u64_t* bits  = (u64_t*)ws;

    prep_kernel<<<NN, 128, 0, stream>>>(x, a, xtb, wh1, wh2);
    swizzle_kernel<<<NN / 32, 256, 0, stream>>>(xtb, xtB);
    bitify_kernel<<<NN, 256, 0, stream>>>(adj, bits);
    attn_kernel<<<dim3(NN / 64, CSPLIT), 256, 0, stream>>>(
        bits, xtB, wh1, wh2, pout, plsum);
    reduce_kernel<<<NN, 128, 0, stream>>>(pout, plsum, out);
}